// Round 2
// baseline (90.159 us; speedup 1.0000x reference)
//
#include <hip/hip_runtime.h>

// EncoderSDP: masked path-max gather. B=16, L=512, P=32, D=256.
// out[b,l] = concat(max_p inputs[b,lpath[p]], max_p inputs[b,rpath[p]]), 0 for l>=sent.
//
// R4 design: R2->R3 showed the kernel is insensitive to both serial trip count
// (5.5->2.5: null) and padded row count (20->24 rows: null). Revised model:
// per-CU outstanding-miss capacity. Random 1KB row gathers miss L1 on all 16
// lines each; ~128-line miss queue x ~500cyc latency ~= 16B/cyc/CU effective
// gather BW -> ~1MB unique/CU -> ~39us. Matches measurement and both nulls
// (pad rows are L1-hit dups; trips are irrelevant under queue backpressure).
//
// Fix: take gathers off the miss path. Each block owns (b, D-quarter q,
// L-chunk) and stages inputs[b,:,q*64..q*64+63] (512 rows x 256B = 128KB)
// into LDS via global_load_lds (sequential/coalesced), then gathers are
// ds_read_b32: row-quarter = 64 lanes x 1 dword, bank = lane%32 -> 2-way
// aliasing = free. Grid 16x4x4 = 256 blocks (1/CU), 1024 threads = 16 waves.
//  - b = blockIdx.x%16 -> XCD = b%8: 2 batches/XCD, slab re-stages L2-hit.
//  - per wave: 16 (l,side) pairs, A/B software pipeline: next pair's 32
//    indices (2x s_load_dwordx16) issued while current pair gathers from LDS.
//  - dead pairs (l >= sent) write zeros, skip gathers; fully-dead blocks
//    skip staging.
//  - 128KB dynamic LDS (needs hipFuncSetAttribute once; host-side, capture-safe).

constexpr int BB = 16;
constexpr int LL = 512;
constexpr int PP = 32;
constexpr int DD = 256;
constexpr int DQ = 64;            // floats per D-quarter staged per block
constexpr int NQ = DD / DQ;       // 4
constexpr int NLS = 4;            // L splits
constexpr int LS  = LL / NLS;     // 128 l's per block
constexpr int THREADS = 1024;
constexpr int WAVES = THREADS / 64;       // 16
constexpr int NPAIR = LS * 2;             // 256 (l,side) pairs per block
constexpr int PER_WAVE = NPAIR / WAVES;   // 16

typedef const __attribute__((address_space(1))) unsigned int* gptr1;
typedef __attribute__((address_space(3))) unsigned int* lptr3;

struct PairState {
    int idx[PP];
    int len;
    int l;
    int side;
    bool alive;
};

__device__ __forceinline__ void load_pair(PairState& s, int pid, int b, int lbase, int sl,
                                          const int* __restrict__ lp, const int* __restrict__ rp,
                                          const int* __restrict__ llen, const int* __restrict__ rlen) {
    s.side = pid & 1;
    s.l    = lbase + (pid >> 1);
    s.alive = (s.l < sl);
    s.len  = 1;
    if (s.alive) {
        const int bl = __builtin_amdgcn_readfirstlane(b * LL + s.l);
        const int* pb = (s.side ? rp : lp) + (size_t)bl * PP;
        s.len = __builtin_amdgcn_readfirstlane((s.side ? rlen : llen)[bl]);   // >= 1
#pragma unroll
        for (int k = 0; k < PP; ++k) s.idx[k] = pb[k];   // 2x s_load_dwordx16
    }
}

__device__ __forceinline__ float chunk_max(const PairState& s, const float* lds, int base, int lane) {
    const int lm1 = s.len - 1;
    float v[8];
#pragma unroll
    for (int k = 0; k < 8; ++k) {
        const int j = (base + k <= lm1) ? s.idx[base + k] : s.idx[0];  // pad = idx[0], max-idempotent
        v[k] = lds[j * DQ + lane];
    }
    return fmaxf(fmaxf(fmaxf(v[0], v[1]), fmaxf(v[2], v[3])),
                 fmaxf(fmaxf(v[4], v[5]), fmaxf(v[6], v[7])));
}

__device__ __forceinline__ void gather_store(const PairState& s, const float* lds,
                                             int b, int q, int lane, float* __restrict__ out) {
    float* outp = out + ((size_t)(b * LL + s.l)) * (2 * DD) + s.side * DD + q * DQ + lane;
    if (!s.alive) {
        __builtin_nontemporal_store(0.0f, outp);
        return;
    }
    float acc = chunk_max(s, lds, 0, lane);
    if (s.len > 8)  acc = fmaxf(acc, chunk_max(s, lds, 8, lane));
    if (s.len > 16) acc = fmaxf(acc, chunk_max(s, lds, 16, lane));
    if (s.len > 24) acc = fmaxf(acc, chunk_max(s, lds, 24, lane));
    __builtin_nontemporal_store(acc, outp);
}

__global__ __launch_bounds__(THREADS, 4) void encoder_sdp_kernel(
    const float* __restrict__ inputs,      // [B, L, D]
    const int*   __restrict__ left_paths,  // [B, L, P]
    const int*   __restrict__ right_paths, // [B, L, P]
    const int*   __restrict__ left_lens,   // [B, L]
    const int*   __restrict__ right_lens,  // [B, L]
    const int*   __restrict__ sent_lens,   // [B]
    float*       __restrict__ out)         // [B, L, 2*D]
{
    extern __shared__ float lds[];         // [LL][DQ] = 128 KB

    const int tid  = threadIdx.x;
    const int w    = tid >> 6;
    const int lane = tid & 63;

    const int bid   = blockIdx.x;
    const int b     = bid & (BB - 1);      // fastest -> XCD = b%8
    const int qs    = bid >> 4;
    const int q     = qs & (NQ - 1);       // D-quarter
    const int ls    = qs >> 2;             // L-chunk
    const int lbase = ls * LS;

    const int sl = sent_lens[b];           // scalar

    // ---- Stage inputs[b, :, q*DQ .. q*DQ+DQ-1] into LDS (skip if block fully dead) ----
    if (sl > lbase) {
        const float* gsrc = inputs + (size_t)b * LL * DD + q * DQ;
#pragma unroll
        for (int i = 0; i < 8; ++i) {
            const int r0u = __builtin_amdgcn_readfirstlane(i * 64 + w * 4);  // wave-uniform base row
            const int r   = r0u + (lane >> 4);                    // 4 rows x 16 lanes x 16B = 1KB
            const float* gp = gsrc + (size_t)r * DD + (lane & 15) * 4;
            __builtin_amdgcn_global_load_lds((gptr1)gp, (lptr3)&lds[r0u * DQ], 16, 0, 0);
        }
    }

    // Pair pipeline A/B; prefetch pair 0's indices while staging is in flight.
    const int pid0 = w * PER_WAVE;
    PairState A, B;
    load_pair(A, pid0, b, lbase, sl, left_paths, right_paths, left_lens, right_lens);

    asm volatile("s_waitcnt vmcnt(0)" ::: "memory");
    __syncthreads();

    for (int i = 0; i < PER_WAVE; i += 2) {
        load_pair(B, pid0 + i + 1, b, lbase, sl, left_paths, right_paths, left_lens, right_lens);
        gather_store(A, lds, b, q, lane, out);
        if (i + 2 < PER_WAVE)
            load_pair(A, pid0 + i + 2, b, lbase, sl, left_paths, right_paths, left_lens, right_lens);
        gather_store(B, lds, b, q, lane, out);
    }
}

extern "C" void kernel_launch(void* const* d_in, const int* in_sizes, int n_in,
                              void* d_out, int out_size, void* d_ws, size_t ws_size,
                              hipStream_t stream) {
    const float* inputs      = (const float*)d_in[0];
    const int*   left_paths  = (const int*)d_in[1];
    const int*   right_paths = (const int*)d_in[2];
    const int*   left_lens   = (const int*)d_in[3];
    const int*   right_lens  = (const int*)d_in[4];
    const int*   sent_lens   = (const int*)d_in[5];
    float*       out         = (float*)d_out;

    constexpr int LDS_BYTES = LL * DQ * sizeof(float);   // 131072
    static bool init = false;
    if (!init) {
        hipFuncSetAttribute((const void*)encoder_sdp_kernel,
                            hipFuncAttributeMaxDynamicSharedMemorySize, LDS_BYTES);
        init = true;
    }

    encoder_sdp_kernel<<<dim3(BB * NQ * NLS), THREADS, LDS_BYTES, stream>>>(
        inputs, left_paths, right_paths, left_lens, right_lens, sent_lens, out);
}

// Round 3
// 82.771 us; speedup vs baseline: 1.0893x; 1.0893x over previous
//
#include <hip/hip_runtime.h>

// EncoderSDP: masked path-max gather.
// B=16, L=512, P=32, D=256.
// out[b,l] = concat(max_p inputs[b, lpath[p]], max_p inputs[b, rpath[p]]), zeroed for l >= sent_lens[b].
//
// R5 = revert to the R2 (best-measured, 81.6/81.9 us) kernel.
// Evidence from R3/R4: dur_us is dominated by the harness poison/restore floor
// (256 MiB fills at ~42-43 us each + dozens of restore dispatches); the
// encoder kernel never appears in the rocprof top-5 (< 41.5 us even when
// dur_us implied 47), so the kernel itself is single-digit-us and both the
// trip-count cut (R3) and LDS staging (R4) attacked a phantom. This structure
// (high occupancy, 8-wide gather chunks, index prefetch) is the best measured.
//  - 256-thread blocks (4 waves, one l each) -> 32 waves/CU vs 16 with 64-thr blocks.
//  - side = blockIdx.y (block-uniform); per-wave bl forced into SGPRs via
//    readfirstlane so index loads are SMEM and gather addresses are saddr-form.
//  - 8-wide gather chunks with the NEXT chunk's indices prefetched while the
//    current chunk's gathers are in flight -> ~1 memory round trip per chunk,
//    E[ceil(len/8)] = 2.5 chunks per wave.
//  - Tail clamped to pbase[len-1] via uniform selects (max is idempotent).

constexpr int BB = 16;
constexpr int LL = 512;
constexpr int PP = 32;
constexpr int D4 = 64;   // D/4 float4s per row
constexpr int CH = 8;    // gather chunk width

typedef float v4f __attribute__((ext_vector_type(4)));

__device__ __forceinline__ v4f v4max(v4f a, v4f b) {
    v4f r;
    r.x = fmaxf(a.x, b.x);
    r.y = fmaxf(a.y, b.y);
    r.z = fmaxf(a.z, b.z);
    r.w = fmaxf(a.w, b.w);
    return r;
}

__global__ __launch_bounds__(256, 6) void encoder_sdp_kernel(
    const v4f* __restrict__ inputs,      // [B, L, D4]
    const int* __restrict__ left_paths,  // [B, L, P]
    const int* __restrict__ right_paths, // [B, L, P]
    const int* __restrict__ left_lens,   // [B, L]
    const int* __restrict__ right_lens,  // [B, L]
    const int* __restrict__ sent_lens,   // [B]
    v4f*       __restrict__ out)         // [B, L, 2*D4]
{
    const int w    = threadIdx.x >> 6;   // wave 0..3 -> l offset
    const int lane = threadIdx.x & 63;
    const int b    = blockIdx.x & (BB - 1);   // XCD = blk%8 = b%8 -> 2 batches/XCD L2
    const int l    = ((blockIdx.x >> 4) << 2) + w;
    const int side = blockIdx.y;              // 0 = left, 1 = right (block-uniform)
    const int bl   = __builtin_amdgcn_readfirstlane(b * LL + l);

    v4f* outp = out + (size_t)bl * (2 * D4) + side * D4 + lane;

    if (l >= sent_lens[b]) {
        v4f z = {0.f, 0.f, 0.f, 0.f};
        __builtin_nontemporal_store(z, outp);
        return;
    }

    const int* paths = side ? right_paths : left_paths;   // uniform select
    const int* lens  = side ? right_lens  : left_lens;
    const int* pbase = paths + (size_t)bl * PP;

    const int len = __builtin_amdgcn_readfirstlane(lens[bl]);  // >= 1
    const int lm1 = len - 1;

    // Chunk-0 indices + the tail-clamp index, all SMEM loads issued up front.
    int cur[CH];
#pragma unroll
    for (int k = 0; k < CH; ++k) cur[k] = pbase[k];
    const int last = pbase[lm1];

    const v4f* base = inputs + (size_t)b * LL * D4 + lane;

    const float NEGV = -1e30f;
    v4f a0 = {NEGV, NEGV, NEGV, NEGV};
    v4f a1 = a0, a2 = a0, a3 = a0;

    const int nch = (len + CH - 1) / CH;   // 1..4 chunks, uniform
    int p = 0;
    for (int c = 0; c < nch; ++c) {
        // Issue all 8 gathers for the current chunk (indices clamped for tail;
        // all-scalar selects keep addresses in SGPRs).
        v4f v[CH];
#pragma unroll
        for (int k = 0; k < CH; ++k) {
            const int j = (p + k <= lm1) ? cur[k] : last;
            v[k] = base[(size_t)j * D4];
        }
        // Prefetch next chunk's indices while gathers are in flight.
        // (&31 wrap keeps the SMEM access in-bounds; wrapped values are never
        //  selected because of the p+k<=lm1 clamp.)
#pragma unroll
        for (int k = 0; k < CH; ++k) {
            cur[k] = pbase[(p + CH + k) & (PP - 1)];
        }
        // Consume.
        a0 = v4max(a0, v4max(v[0], v[4]));
        a1 = v4max(a1, v4max(v[1], v[5]));
        a2 = v4max(a2, v4max(v[2], v[6]));
        a3 = v4max(a3, v4max(v[3], v[7]));
        p += CH;
    }

    a0 = v4max(v4max(a0, a1), v4max(a2, a3));
    __builtin_nontemporal_store(a0, outp);
}

extern "C" void kernel_launch(void* const* d_in, const int* in_sizes, int n_in,
                              void* d_out, int out_size, void* d_ws, size_t ws_size,
                              hipStream_t stream) {
    const v4f* inputs      = (const v4f*)d_in[0];
    const int* left_paths  = (const int*)d_in[1];
    const int* right_paths = (const int*)d_in[2];
    const int* left_lens   = (const int*)d_in[3];
    const int* right_lens  = (const int*)d_in[4];
    const int* sent_lens   = (const int*)d_in[5];
    v4f*       out         = (v4f*)d_out;

    // grid.x: 16 batches x 128 l-quads; grid.y: side
    encoder_sdp_kernel<<<dim3(BB * (LL / 4), 2), 256, 0, stream>>>(
        inputs, left_paths, right_paths, left_lens, right_lens, sent_lens, out);
}